// Round 7
// baseline (6703.956 us; speedup 1.0000x reference)
//
#include <hip/hip_runtime.h>
#include <hip/hip_bf16.h>

// 2-layer GRU decoder, persistent MFMA kernel. B=128, T=1024, H=200.
// 8 batch-groups (16 batch each) x 16 hidden-slice blocks = 128 blocks.
// Weights live in REGISTERS as bf16 hi/lo MFMA A-fragments; per-step GEMM via
// mfma_f32_16x16x32_bf16 x3 (hi*hi + hi*lo + lo*hi) for fp32-grade precision.
// R10: TAGGED EXCHANGE. h-state crosses blocks as 8-byte {value, step-tag}
// words; the staging load itself is the readiness check (retry only words
// whose tag mismatches). Eliminates the flag store + flag poll round trips
// and the post-poll barrier (3 syncthreads/step instead of 4 + flag phase).
// Flow control is safe with the existing double buffer by induction: a block
// writes h(t+1) only after staging h(t), which implies all peers consumed
// h(t-1). R8/R9 evidence: scope is not a lever (system==agent within noise);
// RMW serialization is not the cost (R8: -380cy); the chain is ~4 dependent
// LLC round trips -> this cuts it to ~2-2.5.
// Workspace doubles (819200 B); launcher checks ws_size and falls back to the
// proven R8 flag kernel if it does not fit (fallback visible in counters:
// WRITE_SIZE == R8's 653 MB).

#define TT 1024
#define HH 200
#define NB 16
#define HS 13
#define KP 232   // hB row stride in ushorts; 464 B = 29*16 -> b128-aligned

typedef __attribute__((ext_vector_type(8))) short short8;
typedef __attribute__((ext_vector_type(4))) float f32x4;
typedef unsigned long long ull;

__device__ __forceinline__ float sigm(float v) { return 1.0f / (1.0f + __expf(-v)); }
__device__ __forceinline__ float tanh_fast(float v) {
  float e = __expf(-2.0f * v);
  return (1.0f - e) / (1.0f + e);
}
__device__ __forceinline__ uint llc_load_u32(const uint* p) {
  return __hip_atomic_load(p, __ATOMIC_RELAXED, __HIP_MEMORY_SCOPE_SYSTEM);
}
__device__ __forceinline__ void llc_store_u32(uint* p, uint v) {
  __hip_atomic_store(p, v, __ATOMIC_RELAXED, __HIP_MEMORY_SCOPE_SYSTEM);
}
// 8-byte tagged-word exchange (agent scope: measured == system, R9).
__device__ __forceinline__ ull ld64(const ull* p) {
  return __hip_atomic_load(p, __ATOMIC_RELAXED, __HIP_MEMORY_SCOPE_AGENT);
}
__device__ __forceinline__ void st64(ull* p, ull v) {
  __hip_atomic_store(p, v, __ATOMIC_RELAXED, __HIP_MEMORY_SCOPE_AGENT);
}
__device__ __forceinline__ float bfu2f(ushort u) {
  return __uint_as_float(((uint)u) << 16);
}
__device__ __forceinline__ ushort f2bfu(float f) {
  __hip_bfloat16 b = __float2bfloat16(f);
  return *(ushort*)&b;
}
__device__ __forceinline__ uint packf(float h) {
  ushort hi = f2bfu(h);
  float  fh = bfu2f(hi);
  ushort lo = f2bfu(h - fh);
  return (uint)hi | ((uint)lo << 16);
}

// ============================ R10: tagged-exchange kernel ===================
__global__ __launch_bounds__(256, 1) void gru2_tag(
    const float* __restrict__ x,
    const float* __restrict__ Wih0, const float* __restrict__ Whh0,
    const float* __restrict__ bih0, const float* __restrict__ bhh0,
    const float* __restrict__ Wih1, const float* __restrict__ Whh1,
    const float* __restrict__ bih1, const float* __restrict__ bhh1,
    const float* __restrict__ Wfc,  const float* __restrict__ bfc,
    float* __restrict__ out,
    ull* __restrict__ h0t, ull* __restrict__ h1t)
{
  __shared__ __align__(16) ushort hBh[2][NB][KP];
  __shared__ __align__(16) ushort hBl[2][NB][KP];
  __shared__ float D[117][17];
  __shared__ float Wi0[39][8];
  __shared__ float bi0[39], bh0[39], bi1[39], bh1[39], bfs[4];
  __shared__ float xc[NB][8];

  const int tid  = threadIdx.x;
  const int wave = tid >> 6;
  const int lane = tid & 63;
  const int m15  = lane & 15;
  const int q    = lane >> 4;

  const int g  = blockIdx.x & 7;
  const int s  = blockIdx.x >> 3;
  const int b0 = g * NB;
  const int j0 = s * HS;
  const int hs = (HH - j0 < HS) ? (HH - j0) : HS;
  const int th   = 3 * hs;
  const int h0r  = 6 * hs;
  const int T0   = (h0r + 15) >> 4;
  const int NT   = T0 + ((th + 15) >> 4);
  const bool isOut = (s == 15);

  // ---- one-time: weight A-fragments into registers (hi/lo bf16) ----
  short8 Ah[2][7], Al[2][7];
  #pragma unroll
  for (int mt = 0; mt < 2; ++mt) {
    const int T = wave * 2 + mt;
    const bool fc  = isOut && (wave == 2) && (mt == 0);
    const bool val = fc || (T < NT);
    #pragma unroll
    for (int kt = 0; kt < 7; ++kt) {
      short8 vh = {0,0,0,0,0,0,0,0}, vl = {0,0,0,0,0,0,0,0};
      #pragma unroll
      for (int j = 0; j < 8; ++j) {
        const int k = kt * 32 + q * 8 + j;
        float w = 0.0f;
        if (val && k < HH) {
          if (fc) {
            if (m15 < 4) w = Wfc[m15 * HH + k];
          } else {
            const int p = T * 16 + m15;
            int r = -1;
            if (p < h0r) r = p;
            else if (p >= T0 * 16 && (p - T0 * 16) < th) r = h0r + (p - T0 * 16);
            if (r >= 0) {
              const int m  = r / th, rr = r - m * th;
              const int qq = rr / hs, jj = rr - qq * hs;
              const float* src = (m == 0) ? Whh0 : ((m == 1) ? Wih1 : Whh1);
              w = src[(qq * HH + j0 + jj) * HH + k];
            }
          }
        }
        const ushort uh = f2bfu(w);
        const ushort ul = f2bfu(w - bfu2f(uh));
        vh[j] = (short)uh; vl[j] = (short)ul;
      }
      Ah[mt][kt] = vh; Al[mt][kt] = vl;
    }
  }

  // ---- one-time: small LDS tables ----
  for (int u = tid; u < th * 8; u += 256) {
    int rr = u >> 3, c = u & 7;
    int qq = rr / hs, jj = rr - qq * hs;
    Wi0[rr][c] = Wih0[(qq * HH + j0 + jj) * 8 + c];
  }
  for (int u = tid; u < th; u += 256) {
    int qq = u / hs, jj = u - qq * hs;
    int grow = qq * HH + j0 + jj;
    bi0[u] = bih0[grow]; bh0[u] = bhh0[grow];
    bi1[u] = bih1[grow]; bh1[u] = bhh1[grow];
  }
  if (tid < 4) bfs[tid] = bfc[tid];
  for (int u = tid; u < 2 * NB * KP / 2; u += 256) ((uint*)hBh)[u] = 0;
  for (int u = tid; u < 2 * NB * KP / 2; u += 256) ((uint*)hBl)[u] = 0;
  if (tid < 128 && (tid & 7) >= 4)   // emotion columns: t-invariant
    xc[tid >> 3][tid & 7] = x[(b0 + (tid >> 3)) * TT * 8 + (tid & 7)];
  __syncthreads();

  // ---- per-thread staging constants: word i covers u = tid + i*256 ----
  // u in [0,6400): st=u/3200, b=(u%3200)/200, k=u%200. su = (b0+b)*200+k.
  int su[25]; uint stmask = 0;
  #pragma unroll
  for (int i = 0; i < 25; ++i) {
    const int u = tid + i * 256;
    const int st = u / 3200, rem = u - st * 3200;
    const int b = rem / 200, k = rem - b * 200;
    su[i] = (b0 + b) * HH + k;
    stmask |= (uint)st << i;
  }

  const int cj = tid >> 4, cb = tid & 15;
  const int xb = tid >> 3, xcc7 = tid & 7;

  for (int t = 0; t <= TT + 1; ++t) {
    // ---- hoist teacher-forcing x load ----
    float xtf = 1.0f;
    if (tid < 128 && xcc7 < 4 && t > 0 && t < TT)
      xtf = x[((b0 + xb) * TT + (t - 1)) * 8 + xcc7];

    // ---- tagged staging: load 25 {val,tag} words, retry mismatches ----
    // Consumer at t reads words written at iteration t-1 (tag t) in both
    // state arrays. h0 unchecked at t==TT+1 (values unused); h1 expects
    // tag 0 (memset) for t<=1 (initial zero state).
    const int s0 = ((t + 1) & 1) * 25600;   // h0 slot base (ull elems)
    const int s1 = (t & 1) * 25600;         // h1 slot base
    ull w[25];
    #pragma unroll
    for (int i = 0; i < 25; ++i) {
      const ull* p = (((stmask >> i) & 1) ? h1t + s1 : h0t + s0) + su[i];
      w[i] = ld64(p);
    }
    {
      const uint etag0 = (uint)t;
      const uint etag1 = (t >= 2) ? (uint)t : 0u;
      const bool chk0  = (t <= TT);
      uint pend = 0x1ffffffu;
      // Bounded retry (fail-visible, not harness-killing): legit retries
      // touch only the laggard's ~13-word slice, spread across lines.
      for (int it = 0; it < 200000; ++it) {
        uint np = 0;
        #pragma unroll
        for (int i = 0; i < 25; ++i) {
          if (pend & (1u << i)) {
            const bool is1 = (stmask >> i) & 1;
            const uint et  = is1 ? etag1 : etag0;
            if ((is1 || chk0) && (uint)(w[i] >> 32) != et) {
              const ull* p = (is1 ? h1t + s1 : h0t + s0) + su[i];
              w[i] = ld64(p);
              np |= 1u << i;
            }
          }
        }
        pend = np;
        if (!np) break;
      }
    }
    // ---- unpack values into LDS bf16 hi/lo planes ----
    #pragma unroll
    for (int i = 0; i < 25; ++i) {
      const int u = tid + i * 256;
      const int st = u / 3200, rem = u - st * 3200;
      const int b = rem / 200, k = rem - b * 200;
      const uint v = (uint)w[i];
      hBh[st][b][k] = (ushort)(v & 0xffff);
      hBl[st][b][k] = (ushort)(v >> 16);
    }
    if (tid < 128 && xcc7 < 4 && t < TT)
      xc[xb][xcc7] = xtf;
    __syncthreads();

    // ---- MFMA: D[rows x 16 batch] = W * h  (bf16x3) ----
    #pragma unroll
    for (int mt = 0; mt < 2; ++mt) {
      const int T = wave * 2 + mt;
      const bool fc  = isOut && (wave == 2) && (mt == 0);
      const bool val = fc || (T < NT);
      if (!val) continue;
      const int st = fc ? 1 : ((T < T0) ? 0 : 1);
      const ushort* Bh = &hBh[st][m15][0];
      const ushort* Bl = &hBl[st][m15][0];
      f32x4 acc = {0.f, 0.f, 0.f, 0.f};
      #pragma unroll
      for (int kt = 0; kt < 7; ++kt) {
        const short8 bh = *(const short8*)&Bh[kt * 32 + q * 8];
        const short8 bl = *(const short8*)&Bl[kt * 32 + q * 8];
        acc = __builtin_amdgcn_mfma_f32_16x16x32_bf16(Ah[mt][kt], bh, acc, 0, 0, 0);
        acc = __builtin_amdgcn_mfma_f32_16x16x32_bf16(Ah[mt][kt], bl, acc, 0, 0, 0);
        acc = __builtin_amdgcn_mfma_f32_16x16x32_bf16(Al[mt][kt], bh, acc, 0, 0, 0);
      }
      if (fc) {
        if (t >= 2) {
          #pragma unroll
          for (int i = 0; i < 4; ++i) {
            const int p = q * 4 + i;
            if (p < 4)
              out[((b0 + m15) * TT + (t - 2)) * 4 + p] = tanh_fast(acc[i] + bfs[p]);
          }
        }
      } else {
        #pragma unroll
        for (int i = 0; i < 4; ++i) {
          const int p = T * 16 + q * 4 + i;
          int r = -1;
          if (p < h0r) r = p;
          else if (p >= T0 * 16 && (p - T0 * 16) < th) r = h0r + (p - T0 * 16);
          if (r >= 0) D[r][m15] = acc[i];
        }
      }
    }
    __syncthreads();

    // ---- gate combine + tagged state stores (tag = t+1) ----
    if (cj < hs) {
      const float hv0 = bfu2f(hBh[0][cb][j0 + cj]) + bfu2f(hBl[0][cb][j0 + cj]);
      const float hv1 = bfu2f(hBh[1][cb][j0 + cj]) + bfu2f(hBl[1][cb][j0 + cj]);
      const ull tag = ((ull)(uint)(t + 1)) << 32;
      if (t < TT) {                       // h0(t)
        float ir = bi0[cj], iz = bi0[hs + cj], in_ = bi0[2 * hs + cj];
        #pragma unroll
        for (int c = 0; c < 8; ++c) {
          const float xv = xc[cb][c];
          ir  += Wi0[cj][c] * xv;
          iz  += Wi0[hs + cj][c] * xv;
          in_ += Wi0[2 * hs + cj][c] * xv;
        }
        const float hr = D[cj][cb] + bh0[cj];
        const float hz = D[hs + cj][cb] + bh0[hs + cj];
        const float hn = D[2 * hs + cj][cb] + bh0[2 * hs + cj];
        const float r = sigm(ir + hr), z = sigm(iz + hz);
        const float n = tanh_fast(in_ + r * hn);
        st64(&h0t[(t & 1) * 25600 + (b0 + cb) * HH + j0 + cj],
             (ull)packf((1.0f - z) * n + z * hv0) | tag);
      }
      if (t >= 1 && t <= TT) {            // h1(t-1)
        const float ir  = D[3 * hs + cj][cb] + bi1[cj];
        const float iz  = D[4 * hs + cj][cb] + bi1[hs + cj];
        const float in_ = D[5 * hs + cj][cb] + bi1[2 * hs + cj];
        const float hr  = D[6 * hs + cj][cb] + bh1[cj];
        const float hz  = D[7 * hs + cj][cb] + bh1[hs + cj];
        const float hn  = D[8 * hs + cj][cb] + bh1[2 * hs + cj];
        const float r = sigm(ir + hr), z = sigm(iz + hz);
        const float n = tanh_fast(in_ + r * hn);
        st64(&h1t[((t + 1) & 1) * 25600 + (b0 + cb) * HH + j0 + cj],
             (ull)packf((1.0f - z) * n + z * hv1) | tag);
      }
    }
    // Protects LDS (hB/xc/D) for next stage; also drains this block's
    // stores (harmless -- consumers don't wait on our drain, only on the
    // stores landing, which happens during it).
    __syncthreads();
  }
}

// ===================== fallback: R8 flag kernel (proven, 2998 us) ===========
__global__ __launch_bounds__(256, 1) void gru2_flag(
    const float* __restrict__ x,
    const float* __restrict__ Wih0, const float* __restrict__ Whh0,
    const float* __restrict__ bih0, const float* __restrict__ bhh0,
    const float* __restrict__ Wih1, const float* __restrict__ Whh1,
    const float* __restrict__ bih1, const float* __restrict__ bhh1,
    const float* __restrict__ Wfc,  const float* __restrict__ bfc,
    float* __restrict__ out,
    uint* __restrict__ h0g, uint* __restrict__ h1g, uint* __restrict__ syncp)
{
  __shared__ __align__(16) ushort hBh[2][NB][KP];
  __shared__ __align__(16) ushort hBl[2][NB][KP];
  __shared__ float D[117][17];
  __shared__ float Wi0[39][8];
  __shared__ float bi0[39], bh0[39], bi1[39], bh1[39], bfs[4];
  __shared__ float xc[NB][8];

  const int tid  = threadIdx.x;
  const int wave = tid >> 6;
  const int lane = tid & 63;
  const int m15  = lane & 15;
  const int q    = lane >> 4;

  const int g  = blockIdx.x & 7;
  const int s  = blockIdx.x >> 3;
  const int b0 = g * NB;
  const int j0 = s * HS;
  const int hs = (HH - j0 < HS) ? (HH - j0) : HS;
  const int th   = 3 * hs;
  const int h0r  = 6 * hs;
  const int T0   = (h0r + 15) >> 4;
  const int NT   = T0 + ((th + 15) >> 4);
  const bool isOut = (s == 15);

  uint* flags = syncp;

  short8 Ah[2][7], Al[2][7];
  #pragma unroll
  for (int mt = 0; mt < 2; ++mt) {
    const int T = wave * 2 + mt;
    const bool fc  = isOut && (wave == 2) && (mt == 0);
    const bool val = fc || (T < NT);
    #pragma unroll
    for (int kt = 0; kt < 7; ++kt) {
      short8 vh = {0,0,0,0,0,0,0,0}, vl = {0,0,0,0,0,0,0,0};
      #pragma unroll
      for (int j = 0; j < 8; ++j) {
        const int k = kt * 32 + q * 8 + j;
        float w = 0.0f;
        if (val && k < HH) {
          if (fc) {
            if (m15 < 4) w = Wfc[m15 * HH + k];
          } else {
            const int p = T * 16 + m15;
            int r = -1;
            if (p < h0r) r = p;
            else if (p >= T0 * 16 && (p - T0 * 16) < th) r = h0r + (p - T0 * 16);
            if (r >= 0) {
              const int m  = r / th, rr = r - m * th;
              const int qq = rr / hs, jj = rr - qq * hs;
              const float* src = (m == 0) ? Whh0 : ((m == 1) ? Wih1 : Whh1);
              w = src[(qq * HH + j0 + jj) * HH + k];
            }
          }
        }
        const ushort uh = f2bfu(w);
        const ushort ul = f2bfu(w - bfu2f(uh));
        vh[j] = (short)uh; vl[j] = (short)ul;
      }
      Ah[mt][kt] = vh; Al[mt][kt] = vl;
    }
  }

  for (int u = tid; u < th * 8; u += 256) {
    int rr = u >> 3, c = u & 7;
    int qq = rr / hs, jj = rr - qq * hs;
    Wi0[rr][c] = Wih0[(qq * HH + j0 + jj) * 8 + c];
  }
  for (int u = tid; u < th; u += 256) {
    int qq = u / hs, jj = u - qq * hs;
    int grow = qq * HH + j0 + jj;
    bi0[u] = bih0[grow]; bh0[u] = bhh0[grow];
    bi1[u] = bih1[grow]; bh1[u] = bhh1[grow];
  }
  if (tid < 4) bfs[tid] = bfc[tid];
  for (int u = tid; u < 2 * NB * KP / 2; u += 256) ((uint*)hBh)[u] = 0;
  for (int u = tid; u < 2 * NB * KP / 2; u += 256) ((uint*)hBl)[u] = 0;
  if (tid < 128 && (tid & 7) >= 4)
    xc[tid >> 3][tid & 7] = x[(b0 + (tid >> 3)) * TT * 8 + (tid & 7)];
  __syncthreads();

  const int cj = tid >> 4, cb = tid & 15;
  const int xb = tid >> 3, xcc7 = tid & 7;

  for (int t = 0; t <= TT + 1; ++t) {
    float xtf = 1.0f;
    if (tid < 128 && xcc7 < 4 && t > 0 && t < TT)
      xtf = x[((b0 + xb) * TT + (t - 1)) * 8 + xcc7];

    const uint* h0src = h0g + ((t + 1) & 1) * (128 * HH);
    const uint* h1src = h1g + (t & 1) * (128 * HH);
    uint tmp[25];
    #pragma unroll
    for (int i = 0; i < 25; ++i) {
      const int u  = tid + i * 256;
      const int st = u / 3200, rem = u - st * 3200;
      const int b  = rem / 200, k = rem - b * 200;
      tmp[i] = llc_load_u32(&(st ? h1src : h0src)[(b0 + b) * HH + k]);
    }
    #pragma unroll
    for (int i = 0; i < 25; ++i) {
      const int u  = tid + i * 256;
      const int st = u / 3200, rem = u - st * 3200;
      const int b  = rem / 200, k = rem - b * 200;
      hBh[st][b][k] = (ushort)(tmp[i] & 0xffff);
      hBl[st][b][k] = (ushort)(tmp[i] >> 16);
    }
    if (tid < 128 && xcc7 < 4 && t < TT)
      xc[xb][xcc7] = xtf;
    __syncthreads();

    #pragma unroll
    for (int mt = 0; mt < 2; ++mt) {
      const int T = wave * 2 + mt;
      const bool fc  = isOut && (wave == 2) && (mt == 0);
      const bool val = fc || (T < NT);
      if (!val) continue;
      const int st = fc ? 1 : ((T < T0) ? 0 : 1);
      const ushort* Bh = &hBh[st][m15][0];
      const ushort* Bl = &hBl[st][m15][0];
      f32x4 acc = {0.f, 0.f, 0.f, 0.f};
      #pragma unroll
      for (int kt = 0; kt < 7; ++kt) {
        const short8 bh = *(const short8*)&Bh[kt * 32 + q * 8];
        const short8 bl = *(const short8*)&Bl[kt * 32 + q * 8];
        acc = __builtin_amdgcn_mfma_f32_16x16x32_bf16(Ah[mt][kt], bh, acc, 0, 0, 0);
        acc = __builtin_amdgcn_mfma_f32_16x16x32_bf16(Ah[mt][kt], bl, acc, 0, 0, 0);
        acc = __builtin_amdgcn_mfma_f32_16x16x32_bf16(Al[mt][kt], bh, acc, 0, 0, 0);
      }
      if (fc) {
        if (t >= 2) {
          #pragma unroll
          for (int i = 0; i < 4; ++i) {
            const int p = q * 4 + i;
            if (p < 4)
              out[((b0 + m15) * TT + (t - 2)) * 4 + p] = tanh_fast(acc[i] + bfs[p]);
          }
        }
      } else {
        #pragma unroll
        for (int i = 0; i < 4; ++i) {
          const int p = T * 16 + q * 4 + i;
          int r = -1;
          if (p < h0r) r = p;
          else if (p >= T0 * 16 && (p - T0 * 16) < th) r = h0r + (p - T0 * 16);
          if (r >= 0) D[r][m15] = acc[i];
        }
      }
    }
    __syncthreads();

    if (cj < hs) {
      const float hv0 = bfu2f(hBh[0][cb][j0 + cj]) + bfu2f(hBl[0][cb][j0 + cj]);
      const float hv1 = bfu2f(hBh[1][cb][j0 + cj]) + bfu2f(hBl[1][cb][j0 + cj]);
      if (t < TT) {
        float ir = bi0[cj], iz = bi0[hs + cj], in_ = bi0[2 * hs + cj];
        #pragma unroll
        for (int c = 0; c < 8; ++c) {
          const float xv = xc[cb][c];
          ir  += Wi0[cj][c] * xv;
          iz  += Wi0[hs + cj][c] * xv;
          in_ += Wi0[2 * hs + cj][c] * xv;
        }
        const float hr = D[cj][cb] + bh0[cj];
        const float hz = D[hs + cj][cb] + bh0[hs + cj];
        const float hn = D[2 * hs + cj][cb] + bh0[2 * hs + cj];
        const float r = sigm(ir + hr), z = sigm(iz + hz);
        const float n = tanh_fast(in_ + r * hn);
        llc_store_u32(&h0g[(t & 1) * (128 * HH) + (b0 + cb) * HH + j0 + cj],
                      packf((1.0f - z) * n + z * hv0));
      }
      if (t >= 1 && t <= TT) {
        const float ir  = D[3 * hs + cj][cb] + bi1[cj];
        const float iz  = D[4 * hs + cj][cb] + bi1[hs + cj];
        const float in_ = D[5 * hs + cj][cb] + bi1[2 * hs + cj];
        const float hr  = D[6 * hs + cj][cb] + bh1[cj];
        const float hz  = D[7 * hs + cj][cb] + bh1[hs + cj];
        const float hn  = D[8 * hs + cj][cb] + bh1[2 * hs + cj];
        const float r = sigm(ir + hr), z = sigm(iz + hz);
        const float n = tanh_fast(in_ + r * hn);
        llc_store_u32(&h1g[((t + 1) & 1) * (128 * HH) + (b0 + cb) * HH + j0 + cj],
                      packf((1.0f - z) * n + z * hv1));
      }
    }

    __syncthreads();
    if (tid == 0)
      llc_store_u32(&flags[g * 64 + s * 4], (uint)(t + 1));
    if (wave == 0) {
      const uint tgt = (uint)(t + 1);
      const uint* fp = &flags[g * 64 + (lane & 15) * 4];
      for (int it = 0; it < 200000; ++it) {
        uint v = tgt;
        if (lane < 16) v = llc_load_u32(fp);
        if (__all((int)(v >= tgt))) break;
        __builtin_amdgcn_s_sleep(1);
      }
    }
    __syncthreads();
  }
}

extern "C" void kernel_launch(void* const* d_in, const int* in_sizes, int n_in,
                              void* d_out, int out_size, void* d_ws, size_t ws_size,
                              hipStream_t stream) {
  uint* ws = (uint*)d_ws;
  const size_t need_tag = (size_t)204800 * sizeof(uint);   // 819200 B
  if (ws_size >= need_tag) {
    // Tagged-exchange path: h0t[2][128][200] ull @0, h1t[...] @51200 ull.
    hipMemsetAsync(d_ws, 0, need_tag, stream);
    gru2_tag<<<128, 256, 0, stream>>>(
        (const float*)d_in[0],
        (const float*)d_in[1], (const float*)d_in[2],
        (const float*)d_in[3], (const float*)d_in[4],
        (const float*)d_in[5], (const float*)d_in[6],
        (const float*)d_in[7], (const float*)d_in[8],
        (const float*)d_in[9], (const float*)d_in[10],
        (float*)d_out, (ull*)d_ws, ((ull*)d_ws) + 51200);
  } else {
    // Proven R8 fallback: h0g @0, h1g @51200, flags @102400 (u32).
    hipMemsetAsync(d_ws, 0, (size_t)(102400 + 512) * sizeof(uint), stream);
    gru2_flag<<<128, 256, 0, stream>>>(
        (const float*)d_in[0],
        (const float*)d_in[1], (const float*)d_in[2],
        (const float*)d_in[3], (const float*)d_in[4],
        (const float*)d_in[5], (const float*)d_in[6],
        (const float*)d_in[7], (const float*)d_in[8],
        (const float*)d_in[9], (const float*)d_in[10],
        (float*)d_out, ws, ws + 51200, ws + 102400);
  }
}

// Round 8
// 3269.839 us; speedup vs baseline: 2.0502x; 2.0502x over previous
//
#include <hip/hip_runtime.h>
#include <hip/hip_bf16.h>

// 2-layer GRU decoder, persistent MFMA kernel. B=128, T=1024, H=200.
// 8 batch-groups (16 batch each) x 16 hidden-slice blocks = 128 blocks.
// Weights live in REGISTERS as bf16 hi/lo MFMA A-fragments; per-step GEMM via
// mfma_f32_16x16x32_bf16 x3 (hi*hi + hi*lo + lo*hi) for fp32-grade precision.
// R11 = R8 flag-barrier structure with ONE change: the h exchange layout is
// TRANSPOSED to h[buf][k][g*32+b]. R8's layout h[b][k] made gate-phase lanes
// store dwords 800 B apart -> 416 partial-line write-through transactions per
// block-step (WRITE_SIZE 653 MB vs 54 MB app data, 12x amplification) and a
// slow vmcnt(0) drain. Transposed: 16 lanes store one contiguous 64-B segment
// (26 segments/block-step), each group owns aligned 128-B lines. Flags move
// into the h1 padding slots, contiguous per group -> poll = 1 line-fetch per
// iteration (was 16). Staging loads remain fully coalesced (b fastest).
// Lessons held: one poller wave per block (R7/R10: poll concurrency kills the
// LLC); scope is not a lever (R9); RMW chain is not the cost (R8).
// Workspace 819200 B (proven available: R10 ran this size); R8 fallback kept.

#define TT 1024
#define HH 200
#define NB 16
#define HS 13
#define KP 232   // hB row stride in ushorts; 464 B = 29*16 -> b128-aligned

typedef __attribute__((ext_vector_type(8))) short short8;
typedef __attribute__((ext_vector_type(4))) float f32x4;

__device__ __forceinline__ float sigm(float v) { return 1.0f / (1.0f + __expf(-v)); }
__device__ __forceinline__ float tanh_fast(float v) {
  float e = __expf(-2.0f * v);
  return (1.0f - e) / (1.0f + e);
}
__device__ __forceinline__ uint llc_load_u32(const uint* p) {
  return __hip_atomic_load(p, __ATOMIC_RELAXED, __HIP_MEMORY_SCOPE_SYSTEM);
}
__device__ __forceinline__ void llc_store_u32(uint* p, uint v) {
  __hip_atomic_store(p, v, __ATOMIC_RELAXED, __HIP_MEMORY_SCOPE_SYSTEM);
}
__device__ __forceinline__ float bfu2f(ushort u) {
  return __uint_as_float(((uint)u) << 16);
}
__device__ __forceinline__ ushort f2bfu(float f) {
  __hip_bfloat16 b = __float2bfloat16(f);
  return *(ushort*)&b;
}
__device__ __forceinline__ uint packf(float h) {
  ushort hi = f2bfu(h);
  float  fh = bfu2f(hi);
  ushort lo = f2bfu(h - fh);
  return (uint)hi | ((uint)lo << 16);
}

// ================= R11: transposed-layout kernel (h[buf][k][g*32+b]) ========
// ws u32 map: h0 @0 (2 bufs x 200 k x 256), h1 @102400 (same),
// flags inside h1 pad: flag(g,s) = ws[102400 + g*32 + 16 + s]
// (h data uses only b=0..15 of each 32-slot group; 16..31 free; the flag
//  region lives in h1 buf0 k=0 pads -- never read/written by h traffic).
__global__ __launch_bounds__(256, 1) void gru2_tr(
    const float* __restrict__ x,
    const float* __restrict__ Wih0, const float* __restrict__ Whh0,
    const float* __restrict__ bih0, const float* __restrict__ bhh0,
    const float* __restrict__ Wih1, const float* __restrict__ Whh1,
    const float* __restrict__ bih1, const float* __restrict__ bhh1,
    const float* __restrict__ Wfc,  const float* __restrict__ bfc,
    float* __restrict__ out,
    uint* __restrict__ h0g, uint* __restrict__ h1g)
{
  __shared__ __align__(16) ushort hBh[2][NB][KP];
  __shared__ __align__(16) ushort hBl[2][NB][KP];
  __shared__ float D[117][17];
  __shared__ float Wi0[39][8];
  __shared__ float bi0[39], bh0[39], bi1[39], bh1[39], bfs[4];
  __shared__ float xc[NB][8];

  const int tid  = threadIdx.x;
  const int wave = tid >> 6;
  const int lane = tid & 63;
  const int m15  = lane & 15;
  const int q    = lane >> 4;

  const int g  = blockIdx.x & 7;
  const int s  = blockIdx.x >> 3;
  const int b0 = g * NB;
  const int g32 = g * 32;
  const int j0 = s * HS;
  const int hs = (HH - j0 < HS) ? (HH - j0) : HS;
  const int th   = 3 * hs;
  const int h0r  = 6 * hs;
  const int T0   = (h0r + 15) >> 4;
  const int NT   = T0 + ((th + 15) >> 4);
  const bool isOut = (s == 15);

  uint* flags = h1g + 16;   // flag(g,s) = flags[g*32 + s], 64 B contiguous/group

  // ---- one-time: weight A-fragments into registers (hi/lo bf16) ----
  short8 Ah[2][7], Al[2][7];
  #pragma unroll
  for (int mt = 0; mt < 2; ++mt) {
    const int T = wave * 2 + mt;
    const bool fc  = isOut && (wave == 2) && (mt == 0);
    const bool val = fc || (T < NT);
    #pragma unroll
    for (int kt = 0; kt < 7; ++kt) {
      short8 vh = {0,0,0,0,0,0,0,0}, vl = {0,0,0,0,0,0,0,0};
      #pragma unroll
      for (int j = 0; j < 8; ++j) {
        const int k = kt * 32 + q * 8 + j;
        float w = 0.0f;
        if (val && k < HH) {
          if (fc) {
            if (m15 < 4) w = Wfc[m15 * HH + k];
          } else {
            const int p = T * 16 + m15;
            int r = -1;
            if (p < h0r) r = p;
            else if (p >= T0 * 16 && (p - T0 * 16) < th) r = h0r + (p - T0 * 16);
            if (r >= 0) {
              const int m  = r / th, rr = r - m * th;
              const int qq = rr / hs, jj = rr - qq * hs;
              const float* src = (m == 0) ? Whh0 : ((m == 1) ? Wih1 : Whh1);
              w = src[(qq * HH + j0 + jj) * HH + k];
            }
          }
        }
        const ushort uh = f2bfu(w);
        const ushort ul = f2bfu(w - bfu2f(uh));
        vh[j] = (short)uh; vl[j] = (short)ul;
      }
      Ah[mt][kt] = vh; Al[mt][kt] = vl;
    }
  }

  // ---- one-time: small LDS tables ----
  for (int u = tid; u < th * 8; u += 256) {
    int rr = u >> 3, c = u & 7;
    int qq = rr / hs, jj = rr - qq * hs;
    Wi0[rr][c] = Wih0[(qq * HH + j0 + jj) * 8 + c];
  }
  for (int u = tid; u < th; u += 256) {
    int qq = u / hs, jj = u - qq * hs;
    int grow = qq * HH + j0 + jj;
    bi0[u] = bih0[grow]; bh0[u] = bhh0[grow];
    bi1[u] = bih1[grow]; bh1[u] = bhh1[grow];
  }
  if (tid < 4) bfs[tid] = bfc[tid];
  for (int u = tid; u < 2 * NB * KP / 2; u += 256) ((uint*)hBh)[u] = 0;
  for (int u = tid; u < 2 * NB * KP / 2; u += 256) ((uint*)hBl)[u] = 0;
  if (tid < 128 && (tid & 7) >= 4)   // emotion columns: t-invariant
    xc[tid >> 3][tid & 7] = x[(b0 + (tid >> 3)) * TT * 8 + (tid & 7)];
  __syncthreads();

  const int cj = tid >> 4, cb = tid & 15;
  const int xb = tid >> 3, xcc7 = tid & 7;

  for (int t = 0; t <= TT + 1; ++t) {
    // ---- hoist teacher-forcing x load ----
    float xtf = 1.0f;
    if (tid < 128 && xcc7 < 4 && t > 0 && t < TT)
      xtf = x[((b0 + xb) * TT + (t - 1)) * 8 + xcc7];

    // ---- stage h0(t-1), h1(t-2): transposed layout, fully coalesced ----
    // word u = tid + i*256 in [0,6400): st=u/3200, k=(u%3200)/16, b=u%16.
    // addr = buf + k*256 + g*32 + b -> 16 consecutive lanes = 64 B segment.
    const uint* p0 = h0g + ((t + 1) & 1) * 51200;
    const uint* p1 = h1g + (t & 1) * 51200;
    uint tmp[25];
    #pragma unroll
    for (int i = 0; i < 25; ++i) {
      const int u  = tid + i * 256;
      const int st = u / 3200, r = u - st * 3200;
      const int k  = r >> 4, b = r & 15;
      tmp[i] = llc_load_u32(&(st ? p1 : p0)[k * 256 + g32 + b]);
    }
    #pragma unroll
    for (int i = 0; i < 25; ++i) {
      const int u  = tid + i * 256;
      const int st = u / 3200, r = u - st * 3200;
      const int k  = r >> 4, b = r & 15;
      hBh[st][b][k] = (ushort)(tmp[i] & 0xffff);
      hBl[st][b][k] = (ushort)(tmp[i] >> 16);
    }
    if (tid < 128 && xcc7 < 4 && t < TT)
      xc[xb][xcc7] = xtf;
    __syncthreads();

    // ---- MFMA: D[rows x 16 batch] = W * h  (bf16x3) ----
    #pragma unroll
    for (int mt = 0; mt < 2; ++mt) {
      const int T = wave * 2 + mt;
      const bool fc  = isOut && (wave == 2) && (mt == 0);
      const bool val = fc || (T < NT);
      if (!val) continue;
      const int st = fc ? 1 : ((T < T0) ? 0 : 1);
      const ushort* Bh = &hBh[st][m15][0];
      const ushort* Bl = &hBl[st][m15][0];
      f32x4 acc = {0.f, 0.f, 0.f, 0.f};
      #pragma unroll
      for (int kt = 0; kt < 7; ++kt) {
        const short8 bh = *(const short8*)&Bh[kt * 32 + q * 8];
        const short8 bl = *(const short8*)&Bl[kt * 32 + q * 8];
        acc = __builtin_amdgcn_mfma_f32_16x16x32_bf16(Ah[mt][kt], bh, acc, 0, 0, 0);
        acc = __builtin_amdgcn_mfma_f32_16x16x32_bf16(Ah[mt][kt], bl, acc, 0, 0, 0);
        acc = __builtin_amdgcn_mfma_f32_16x16x32_bf16(Al[mt][kt], bh, acc, 0, 0, 0);
      }
      if (fc) {
        if (t >= 2) {
          #pragma unroll
          for (int i = 0; i < 4; ++i) {
            const int p = q * 4 + i;
            if (p < 4)
              out[((b0 + m15) * TT + (t - 2)) * 4 + p] = tanh_fast(acc[i] + bfs[p]);
          }
        }
      } else {
        #pragma unroll
        for (int i = 0; i < 4; ++i) {
          const int p = T * 16 + q * 4 + i;
          int r = -1;
          if (p < h0r) r = p;
          else if (p >= T0 * 16 && (p - T0 * 16) < th) r = h0r + (p - T0 * 16);
          if (r >= 0) D[r][m15] = acc[i];
        }
      }
    }
    __syncthreads();

    // ---- gate combine + transposed coalesced stores ----
    // Thread (cj,cb): addr = buf + (j0+cj)*256 + g*32 + cb -> each 16-lane
    // quarter stores one contiguous 64-B segment (26 segments/block-step).
    if (cj < hs) {
      const float hv0 = bfu2f(hBh[0][cb][j0 + cj]) + bfu2f(hBl[0][cb][j0 + cj]);
      const float hv1 = bfu2f(hBh[1][cb][j0 + cj]) + bfu2f(hBl[1][cb][j0 + cj]);
      if (t < TT) {                       // h0(t)
        float ir = bi0[cj], iz = bi0[hs + cj], in_ = bi0[2 * hs + cj];
        #pragma unroll
        for (int c = 0; c < 8; ++c) {
          const float xv = xc[cb][c];
          ir  += Wi0[cj][c] * xv;
          iz  += Wi0[hs + cj][c] * xv;
          in_ += Wi0[2 * hs + cj][c] * xv;
        }
        const float hr = D[cj][cb] + bh0[cj];
        const float hz = D[hs + cj][cb] + bh0[hs + cj];
        const float hn = D[2 * hs + cj][cb] + bh0[2 * hs + cj];
        const float r = sigm(ir + hr), z = sigm(iz + hz);
        const float n = tanh_fast(in_ + r * hn);
        llc_store_u32(&h0g[(t & 1) * 51200 + (j0 + cj) * 256 + g32 + cb],
                      packf((1.0f - z) * n + z * hv0));
      }
      if (t >= 1 && t <= TT) {            // h1(t-1)
        const float ir  = D[3 * hs + cj][cb] + bi1[cj];
        const float iz  = D[4 * hs + cj][cb] + bi1[hs + cj];
        const float in_ = D[5 * hs + cj][cb] + bi1[2 * hs + cj];
        const float hr  = D[6 * hs + cj][cb] + bh1[cj];
        const float hz  = D[7 * hs + cj][cb] + bh1[hs + cj];
        const float hn  = D[8 * hs + cj][cb] + bh1[2 * hs + cj];
        const float r = sigm(ir + hr), z = sigm(iz + hz);
        const float n = tanh_fast(in_ + r * hn);
        llc_store_u32(&h1g[((t + 1) & 1) * 51200 + (j0 + cj) * 256 + g32 + cb],
                      packf((1.0f - z) * n + z * hv1));
      }
    }

    // ---- per-group barrier: flag store + ONE 16-lane 1-line poll ----
    __syncthreads();   // drains all waves' h stores (vmcnt0 before s_barrier)
    if (tid == 0)
      llc_store_u32(&flags[g32 + s], (uint)(t + 1));
    if (wave == 0) {
      const uint tgt = (uint)(t + 1);
      const uint* fp = &flags[g32 + (lane & 15)];   // 16 u32 = 64 B, 1 line
      for (int it = 0; it < 200000; ++it) {
        uint v = tgt;
        if (lane < 16) v = llc_load_u32(fp);
        if (__all((int)(v >= tgt))) break;
        __builtin_amdgcn_s_sleep(1);
      }
    }
    __syncthreads();
  }
}

// ===================== fallback: R8 flag kernel (proven, 2998 us) ===========
__global__ __launch_bounds__(256, 1) void gru2_flag(
    const float* __restrict__ x,
    const float* __restrict__ Wih0, const float* __restrict__ Whh0,
    const float* __restrict__ bih0, const float* __restrict__ bhh0,
    const float* __restrict__ Wih1, const float* __restrict__ Whh1,
    const float* __restrict__ bih1, const float* __restrict__ bhh1,
    const float* __restrict__ Wfc,  const float* __restrict__ bfc,
    float* __restrict__ out,
    uint* __restrict__ h0g, uint* __restrict__ h1g, uint* __restrict__ syncp)
{
  __shared__ __align__(16) ushort hBh[2][NB][KP];
  __shared__ __align__(16) ushort hBl[2][NB][KP];
  __shared__ float D[117][17];
  __shared__ float Wi0[39][8];
  __shared__ float bi0[39], bh0[39], bi1[39], bh1[39], bfs[4];
  __shared__ float xc[NB][8];

  const int tid  = threadIdx.x;
  const int wave = tid >> 6;
  const int lane = tid & 63;
  const int m15  = lane & 15;
  const int q    = lane >> 4;

  const int g  = blockIdx.x & 7;
  const int s  = blockIdx.x >> 3;
  const int b0 = g * NB;
  const int j0 = s * HS;
  const int hs = (HH - j0 < HS) ? (HH - j0) : HS;
  const int th   = 3 * hs;
  const int h0r  = 6 * hs;
  const int T0   = (h0r + 15) >> 4;
  const int NT   = T0 + ((th + 15) >> 4);
  const bool isOut = (s == 15);

  uint* flags = syncp;

  short8 Ah[2][7], Al[2][7];
  #pragma unroll
  for (int mt = 0; mt < 2; ++mt) {
    const int T = wave * 2 + mt;
    const bool fc  = isOut && (wave == 2) && (mt == 0);
    const bool val = fc || (T < NT);
    #pragma unroll
    for (int kt = 0; kt < 7; ++kt) {
      short8 vh = {0,0,0,0,0,0,0,0}, vl = {0,0,0,0,0,0,0,0};
      #pragma unroll
      for (int j = 0; j < 8; ++j) {
        const int k = kt * 32 + q * 8 + j;
        float w = 0.0f;
        if (val && k < HH) {
          if (fc) {
            if (m15 < 4) w = Wfc[m15 * HH + k];
          } else {
            const int p = T * 16 + m15;
            int r = -1;
            if (p < h0r) r = p;
            else if (p >= T0 * 16 && (p - T0 * 16) < th) r = h0r + (p - T0 * 16);
            if (r >= 0) {
              const int m  = r / th, rr = r - m * th;
              const int qq = rr / hs, jj = rr - qq * hs;
              const float* src = (m == 0) ? Whh0 : ((m == 1) ? Wih1 : Whh1);
              w = src[(qq * HH + j0 + jj) * HH + k];
            }
          }
        }
        const ushort uh = f2bfu(w);
        const ushort ul = f2bfu(w - bfu2f(uh));
        vh[j] = (short)uh; vl[j] = (short)ul;
      }
      Ah[mt][kt] = vh; Al[mt][kt] = vl;
    }
  }

  for (int u = tid; u < th * 8; u += 256) {
    int rr = u >> 3, c = u & 7;
    int qq = rr / hs, jj = rr - qq * hs;
    Wi0[rr][c] = Wih0[(qq * HH + j0 + jj) * 8 + c];
  }
  for (int u = tid; u < th; u += 256) {
    int qq = u / hs, jj = u - qq * hs;
    int grow = qq * HH + j0 + jj;
    bi0[u] = bih0[grow]; bh0[u] = bhh0[grow];
    bi1[u] = bih1[grow]; bh1[u] = bhh1[grow];
  }
  if (tid < 4) bfs[tid] = bfc[tid];
  for (int u = tid; u < 2 * NB * KP / 2; u += 256) ((uint*)hBh)[u] = 0;
  for (int u = tid; u < 2 * NB * KP / 2; u += 256) ((uint*)hBl)[u] = 0;
  if (tid < 128 && (tid & 7) >= 4)
    xc[tid >> 3][tid & 7] = x[(b0 + (tid >> 3)) * TT * 8 + (tid & 7)];
  __syncthreads();

  const int cj = tid >> 4, cb = tid & 15;
  const int xb = tid >> 3, xcc7 = tid & 7;

  for (int t = 0; t <= TT + 1; ++t) {
    float xtf = 1.0f;
    if (tid < 128 && xcc7 < 4 && t > 0 && t < TT)
      xtf = x[((b0 + xb) * TT + (t - 1)) * 8 + xcc7];

    const uint* h0src = h0g + ((t + 1) & 1) * (128 * HH);
    const uint* h1src = h1g + (t & 1) * (128 * HH);
    uint tmp[25];
    #pragma unroll
    for (int i = 0; i < 25; ++i) {
      const int u  = tid + i * 256;
      const int st = u / 3200, rem = u - st * 3200;
      const int b  = rem / 200, k = rem - b * 200;
      tmp[i] = llc_load_u32(&(st ? h1src : h0src)[(b0 + b) * HH + k]);
    }
    #pragma unroll
    for (int i = 0; i < 25; ++i) {
      const int u  = tid + i * 256;
      const int st = u / 3200, rem = u - st * 3200;
      const int b  = rem / 200, k = rem - b * 200;
      hBh[st][b][k] = (ushort)(tmp[i] & 0xffff);
      hBl[st][b][k] = (ushort)(tmp[i] >> 16);
    }
    if (tid < 128 && xcc7 < 4 && t < TT)
      xc[xb][xcc7] = xtf;
    __syncthreads();

    #pragma unroll
    for (int mt = 0; mt < 2; ++mt) {
      const int T = wave * 2 + mt;
      const bool fc  = isOut && (wave == 2) && (mt == 0);
      const bool val = fc || (T < NT);
      if (!val) continue;
      const int st = fc ? 1 : ((T < T0) ? 0 : 1);
      const ushort* Bh = &hBh[st][m15][0];
      const ushort* Bl = &hBl[st][m15][0];
      f32x4 acc = {0.f, 0.f, 0.f, 0.f};
      #pragma unroll
      for (int kt = 0; kt < 7; ++kt) {
        const short8 bh = *(const short8*)&Bh[kt * 32 + q * 8];
        const short8 bl = *(const short8*)&Bl[kt * 32 + q * 8];
        acc = __builtin_amdgcn_mfma_f32_16x16x32_bf16(Ah[mt][kt], bh, acc, 0, 0, 0);
        acc = __builtin_amdgcn_mfma_f32_16x16x32_bf16(Ah[mt][kt], bl, acc, 0, 0, 0);
        acc = __builtin_amdgcn_mfma_f32_16x16x32_bf16(Al[mt][kt], bh, acc, 0, 0, 0);
      }
      if (fc) {
        if (t >= 2) {
          #pragma unroll
          for (int i = 0; i < 4; ++i) {
            const int p = q * 4 + i;
            if (p < 4)
              out[((b0 + m15) * TT + (t - 2)) * 4 + p] = tanh_fast(acc[i] + bfs[p]);
          }
        }
      } else {
        #pragma unroll
        for (int i = 0; i < 4; ++i) {
          const int p = T * 16 + q * 4 + i;
          int r = -1;
          if (p < h0r) r = p;
          else if (p >= T0 * 16 && (p - T0 * 16) < th) r = h0r + (p - T0 * 16);
          if (r >= 0) D[r][m15] = acc[i];
        }
      }
    }
    __syncthreads();

    if (cj < hs) {
      const float hv0 = bfu2f(hBh[0][cb][j0 + cj]) + bfu2f(hBl[0][cb][j0 + cj]);
      const float hv1 = bfu2f(hBh[1][cb][j0 + cj]) + bfu2f(hBl[1][cb][j0 + cj]);
      if (t < TT) {
        float ir = bi0[cj], iz = bi0[hs + cj], in_ = bi0[2 * hs + cj];
        #pragma unroll
        for (int c = 0; c < 8; ++c) {
          const float xv = xc[cb][c];
          ir  += Wi0[cj][c] * xv;
          iz  += Wi0[hs + cj][c] * xv;
          in_ += Wi0[2 * hs + cj][c] * xv;
        }
        const float hr = D[cj][cb] + bh0[cj];
        const float hz = D[hs + cj][cb] + bh0[hs + cj];
        const float hn = D[2 * hs + cj][cb] + bh0[2 * hs + cj];
        const float r = sigm(ir + hr), z = sigm(iz + hz);
        const float n = tanh_fast(in_ + r * hn);
        llc_store_u32(&h0g[(t & 1) * (128 * HH) + (b0 + cb) * HH + j0 + cj],
                      packf((1.0f - z) * n + z * hv0));
      }
      if (t >= 1 && t <= TT) {
        const float ir  = D[3 * hs + cj][cb] + bi1[cj];
        const float iz  = D[4 * hs + cj][cb] + bi1[hs + cj];
        const float in_ = D[5 * hs + cj][cb] + bi1[2 * hs + cj];
        const float hr  = D[6 * hs + cj][cb] + bh1[cj];
        const float hz  = D[7 * hs + cj][cb] + bh1[hs + cj];
        const float hn  = D[8 * hs + cj][cb] + bh1[2 * hs + cj];
        const float r = sigm(ir + hr), z = sigm(iz + hz);
        const float n = tanh_fast(in_ + r * hn);
        llc_store_u32(&h1g[((t + 1) & 1) * (128 * HH) + (b0 + cb) * HH + j0 + cj],
                      packf((1.0f - z) * n + z * hv1));
      }
    }

    __syncthreads();
    if (tid == 0)
      llc_store_u32(&flags[g * 64 + s * 4], (uint)(t + 1));
    if (wave == 0) {
      const uint tgt = (uint)(t + 1);
      const uint* fp = &flags[g * 64 + (lane & 15) * 4];
      for (int it = 0; it < 200000; ++it) {
        uint v = tgt;
        if (lane < 16) v = llc_load_u32(fp);
        if (__all((int)(v >= tgt))) break;
        __builtin_amdgcn_s_sleep(1);
      }
    }
    __syncthreads();
  }
}

extern "C" void kernel_launch(void* const* d_in, const int* in_sizes, int n_in,
                              void* d_out, int out_size, void* d_ws, size_t ws_size,
                              hipStream_t stream) {
  uint* ws = (uint*)d_ws;
  const size_t need_tr = (size_t)204800 * sizeof(uint);   // 819200 B
  if (ws_size >= need_tr) {
    // Transposed layout: h0 @0 ([2][200][256] u32), h1 @102400; flags in
    // h1 pad slots (ws[102400 + g*32 + 16 + s]).
    hipMemsetAsync(d_ws, 0, need_tr, stream);
    gru2_tr<<<128, 256, 0, stream>>>(
        (const float*)d_in[0],
        (const float*)d_in[1], (const float*)d_in[2],
        (const float*)d_in[3], (const float*)d_in[4],
        (const float*)d_in[5], (const float*)d_in[6],
        (const float*)d_in[7], (const float*)d_in[8],
        (const float*)d_in[9], (const float*)d_in[10],
        (float*)d_out, ws, ws + 102400);
  } else {
    // Proven R8 fallback: h0g @0, h1g @51200, flags @102400 (u32).
    hipMemsetAsync(d_ws, 0, (size_t)(102400 + 512) * sizeof(uint), stream);
    gru2_flag<<<128, 256, 0, stream>>>(
        (const float*)d_in[0],
        (const float*)d_in[1], (const float*)d_in[2],
        (const float*)d_in[3], (const float*)d_in[4],
        (const float*)d_in[5], (const float*)d_in[6],
        (const float*)d_in[7], (const float*)d_in[8],
        (const float*)d_in[9], (const float*)d_in[10],
        (float*)d_out, ws, ws + 51200, ws + 102400);
  }
}